// Round 2
// baseline (266.162 us; speedup 1.0000x reference)
//
#include <hip/hip_runtime.h>
#include <hip/hip_fp16.h>

// Fused 3-layer ReLU-RNN + linear head, MI355X (gfx950).
// T=512, B=4096, IN=4, H1=24, H2=48, H3=24, OUT=2.
//
// One wave owns 16 batch columns for the whole recurrence (batch = MFMA N,
// neurons = M). Weights live in VGPRs as A-fragments; biases ride as MFMA C.
//
// ROUND 2 change: layer-skewed software pipeline. Iteration i issues
//   L0(step i), L1(step i-1), L2(step i-2), out(step i-3)
// which are mutually independent; all relu+f16 packs at the top of iteration
// i read accumulators from MFMAs issued in iteration i-1, so MFMA result
// latency is fully hidden. 4 fill iterations (template<FILL>) zero the
// packs of invalid pre-steps; 4 drain iterations run with clamped x index.
// Identical arithmetic to the round-1 kernel, just reordered.

#define TSEQ 512
#define NBAT 4096

typedef float    f32x4 __attribute__((ext_vector_type(4)));
typedef _Float16 f16x8 __attribute__((ext_vector_type(8)));

union BFrag { f16x8 h; unsigned u[4]; };

__device__ __forceinline__ f32x4 MF(f16x8 a, f16x8 b, f32x4 c) {
  return __builtin_amdgcn_mfma_f32_16x16x32_f16(a, b, c, 0, 0, 0);
}

__device__ __forceinline__ unsigned pkh(float a, float b) {
  union { __half2 h2; unsigned u; } x;
  x.h2 = __floats2half2_rn(a, b);
  return x.u;
}
__device__ __forceinline__ unsigned pkr(float a, float b) {
  return pkh(fmaxf(a, 0.f), fmaxf(b, 0.f));
}

struct WP {
  const float *wih0, *whh0, *wih1, *whh1, *wih2, *whh2, *wout;
};

// Concatenated-weight view per layer, zero-padded so garbage B slots
// always multiply by 0.
//  L0 (K=32): k<24 -> W_hh0[m][k] (h1_prev), k in [28,32) -> W_ih0[m][k-28] (x_t)
//  L1 (K=96): k<24 -> W_ih1[m][k] (a1),     k in [32,80) -> W_hh1[m][k-32] (h2_prev)
//  L2 (K=96): k<48 -> W_ih2[m][k] (a2),     k in [48,72) -> W_hh2[m][k-48] (h3_prev)
//  L3 (K=32): k<24 -> W_out[m][k] (a3), m<2
__device__ float wcat(int layer, int m, int k, const WP& P) {
  if (layer == 0) {
    if (m < 24) {
      if (k < 24) return P.whh0[m * 24 + k];
      if (k >= 28 && k < 32) return P.wih0[m * 4 + (k - 28)];
    }
    return 0.f;
  } else if (layer == 1) {
    if (m < 48) {
      if (k < 24) return P.wih1[m * 24 + k];
      if (k >= 32 && k < 80) return P.whh1[m * 48 + (k - 32)];
    }
    return 0.f;
  } else if (layer == 2) {
    if (m < 24) {
      if (k < 48) return P.wih2[m * 48 + k];
      if (k >= 48 && k < 72) return P.whh2[m * 24 + (k - 48)];
    }
    return 0.f;
  } else {
    if (m < 2 && k < 24) return P.wout[m * 24 + k];
    return 0.f;
  }
}

// A fragment (16x16x32 f16): lane holds row m = 16*mt + (lane&15),
// slots j<4: k = kc*32 + 4q + j ; slots j>=4: k = kc*32 + 16 + 4q + (j-4).
__device__ f16x8 afrag(int layer, int mt, int kc, const WP& P) {
  int m  = mt * 16 + (threadIdx.x & 15);
  int kb = kc * 32 + 4 * ((threadIdx.x >> 4) & 3);
  f16x8 r;
#pragma unroll
  for (int j = 0; j < 4; ++j) r[j] = (_Float16)wcat(layer, m, kb + j, P);
#pragma unroll
  for (int j = 0; j < 4; ++j) r[4 + j] = (_Float16)wcat(layer, m, kb + 16 + j, P);
  return r;
}

// Bias as C operand: reg i holds bias for neuron m = 16*mt + 4q + i.
__device__ f32x4 cfrag(const float* b1, const float* b2, int mt, int nvalid) {
  int q = (threadIdx.x >> 4) & 3;
  f32x4 r;
#pragma unroll
  for (int i = 0; i < 4; ++i) {
    int m = mt * 16 + 4 * q + i;
    float v = 0.f;
    if (m < nvalid) { v = b1[m]; if (b2) v += b2[m]; }
    r[i] = v;
  }
  return r;
}

struct St {
  // weights / biases (persistent)
  f16x8 A00, A01, A1[3][3], A2[2][3], A3;
  f32x4 C00, C01, C10, C11, C12, C20, C21, C3;
  // loop-carried accumulators (read at top of next iteration)
  f32x4 a10, a11, a20, a21, a22, a30, a31, ao;
  // x pipeline
  float4 xcur, xnxt;
  const float4* x4;
  float2* o2;
  int b0, c, q;
};

// Iteration i: pack results of {L0(i-1),L1(i-2),L2(i-3)} from last iter's
// accs, store out(i-4), then issue MFMAs for L0(i),L1(i-1),L2(i-2),out(i-3).
template<bool FILL>
__device__ __forceinline__ void body(St& s, int i) {
  // ---- store out(i-4) from last iteration's out-MFMA ----
  if (!FILL) {
    if (s.q == 0)
      s.o2[(size_t)(i - 4) * NBAT + s.b0 + s.c] = make_float2(s.ao[0], s.ao[1]);
  }

  // ---- packs (all read accs issued >= 1 iteration ago) ----
  unsigned fa0 = pkr(s.a10[0], s.a10[1]), fa1 = pkr(s.a10[2], s.a10[3]);
  unsigned h1b = pkr(s.a11[0], s.a11[1]), h1c = pkr(s.a11[2], s.a11[3]);
  if (FILL && i < 1) { fa0 = fa1 = h1b = h1c = 0u; }          // h1(-1)=0
  unsigned fb0 = pkr(s.a20[0], s.a20[1]), fb1 = pkr(s.a20[2], s.a20[3]);
  unsigned fb2 = pkr(s.a21[0], s.a21[1]), fb3 = pkr(s.a21[2], s.a21[3]);
  unsigned fc0 = pkr(s.a22[0], s.a22[1]), fc1 = pkr(s.a22[2], s.a22[3]);
  if (FILL && i < 2) { fb0 = fb1 = fb2 = fb3 = fc0 = fc1 = 0u; } // h2(-1)=0
  unsigned fd0 = pkr(s.a30[0], s.a30[1]), fd1 = pkr(s.a30[2], s.a30[3]);
  unsigned fd2 = pkr(s.a31[0], s.a31[1]), fd3 = pkr(s.a31[2], s.a31[3]);
  if (FILL && i < 3) { fd0 = fd1 = fd2 = fd3 = 0u; }          // h3(-1)=0

  // FA = [h1(i-1) | x_i in q3]   (L0(i) chunk0; L1(i-1) chunk0 — x cols are 0)
  BFrag FA, FB, FC, FD, BE;
  FA.u[0] = fa0; FA.u[1] = fa1;
  FA.u[2] = (s.q == 3) ? pkh(s.xcur.x, s.xcur.y) : h1b;
  FA.u[3] = (s.q == 3) ? pkh(s.xcur.z, s.xcur.w) : h1c;
  // FB = [h2(i-2) t0 | t1]       (L1(i-1) chunk1; L2(i-2) chunk0)
  FB.u[0] = fb0; FB.u[1] = fb1; FB.u[2] = fb2; FB.u[3] = fb3;
  // FC = [h2(i-2) t2 | h3(i-3) t0]  (L1(i-1) chunk2 — h3 cols are 0; L2 chunk1)
  FC.u[0] = fc0; FC.u[1] = fc1; FC.u[2] = fd0; FC.u[3] = fd1;
  // BE = [h3(i-3) t1 | 0]        (L2(i-2) chunk2)
  BE.u[0] = fd2; BE.u[1] = fd3; BE.u[2] = 0u; BE.u[3] = 0u;
  // FD = [h3(i-3) t0 | t1]       (out(i-3) chunk0)
  FD.u[0] = fd0; FD.u[1] = fd1; FD.u[2] = fd2; FD.u[3] = fd3;

  // ---- x prefetch (2 iterations ahead, clamped) ----
  int tn = i + 2 < TSEQ ? i + 2 : TSEQ - 1;
  float4 xn = s.x4[(size_t)tn * NBAT + s.b0 + s.c];

  // ---- MFMAs: four independent layer-steps ----
  s.a10 = MF(s.A00, FA.h, s.C00);                 // L0(i)
  s.a11 = MF(s.A01, FA.h, s.C01);

  s.a20 = MF(s.A1[0][0], FA.h, s.C10);            // L1(i-1)
  s.a21 = MF(s.A1[1][0], FA.h, s.C11);
  s.a22 = MF(s.A1[2][0], FA.h, s.C12);
  s.a20 = MF(s.A1[0][1], FB.h, s.a20);
  s.a21 = MF(s.A1[1][1], FB.h, s.a21);
  s.a22 = MF(s.A1[2][1], FB.h, s.a22);
  s.a20 = MF(s.A1[0][2], FC.h, s.a20);
  s.a21 = MF(s.A1[1][2], FC.h, s.a21);
  s.a22 = MF(s.A1[2][2], FC.h, s.a22);

  s.a30 = MF(s.A2[0][0], FB.h, s.C20);            // L2(i-2)
  s.a31 = MF(s.A2[1][0], FB.h, s.C21);
  s.a30 = MF(s.A2[0][1], FC.h, s.a30);
  s.a31 = MF(s.A2[1][1], FC.h, s.a31);
  s.a30 = MF(s.A2[0][2], BE.h, s.a30);
  s.a31 = MF(s.A2[1][2], BE.h, s.a31);

  s.ao = MF(s.A3, FD.h, s.C3);                    // out(i-3)

  s.xcur = s.xnxt;
  s.xnxt = xn;
}

__global__ void __launch_bounds__(64)
rnn3_fused(const float* __restrict__ x,
           const float* __restrict__ wih0, const float* __restrict__ whh0,
           const float* __restrict__ bih0, const float* __restrict__ bhh0,
           const float* __restrict__ wih1, const float* __restrict__ whh1,
           const float* __restrict__ bih1, const float* __restrict__ bhh1,
           const float* __restrict__ wih2, const float* __restrict__ whh2,
           const float* __restrict__ bih2, const float* __restrict__ bhh2,
           const float* __restrict__ wout, const float* __restrict__ bout,
           float* __restrict__ out) {
  const int lane = threadIdx.x;

  St s;
  s.c = lane & 15;
  s.q = lane >> 4;
  s.b0 = blockIdx.x * 16;
  s.x4 = (const float4*)x;
  s.o2 = (float2*)out;

  WP P{wih0, whh0, wih1, whh1, wih2, whh2, wout};

  s.A00 = afrag(0, 0, 0, P);
  s.A01 = afrag(0, 1, 0, P);
#pragma unroll
  for (int mt = 0; mt < 3; ++mt)
#pragma unroll
    for (int kc = 0; kc < 3; ++kc) s.A1[mt][kc] = afrag(1, mt, kc, P);
#pragma unroll
  for (int mt = 0; mt < 2; ++mt)
#pragma unroll
    for (int kc = 0; kc < 3; ++kc) s.A2[mt][kc] = afrag(2, mt, kc, P);
  s.A3 = afrag(3, 0, 0, P);

  s.C00 = cfrag(bih0, bhh0, 0, 24);
  s.C01 = cfrag(bih0, bhh0, 1, 24);
  s.C10 = cfrag(bih1, bhh1, 0, 48);
  s.C11 = cfrag(bih1, bhh1, 1, 48);
  s.C12 = cfrag(bih1, bhh1, 2, 48);
  s.C20 = cfrag(bih2, bhh2, 0, 24);
  s.C21 = cfrag(bih2, bhh2, 1, 24);
  s.C3  = cfrag(bout, nullptr, 0, 2);

  // zero-init accs (fill iterations force invalid packs to 0 anyway,
  // but avoid reading uninitialized registers)
  s.a10 = s.a11 = s.a20 = s.a21 = s.a22 = s.a30 = s.a31 = s.ao =
      f32x4{0.f, 0.f, 0.f, 0.f};

  s.xcur = s.x4[(size_t)0 * NBAT + s.b0 + s.c];  // x_0
  s.xnxt = s.x4[(size_t)1 * NBAT + s.b0 + s.c];  // x_1

  // ---- pipeline fill: iterations 0..3 ----
  body<true>(s, 0);
  body<true>(s, 1);
  body<true>(s, 2);
  body<true>(s, 3);

  // ---- steady state + drain: stores out(0..TSEQ-1) ----
#pragma unroll 1
  for (int i = 4; i < TSEQ + 4; ++i) body<false>(s, i);
}

extern "C" void kernel_launch(void* const* d_in, const int* in_sizes, int n_in,
                              void* d_out, int out_size, void* d_ws, size_t ws_size,
                              hipStream_t stream) {
  const float* x    = (const float*)d_in[0];
  const float* wih0 = (const float*)d_in[1];
  const float* whh0 = (const float*)d_in[2];
  const float* bih0 = (const float*)d_in[3];
  const float* bhh0 = (const float*)d_in[4];
  const float* wih1 = (const float*)d_in[5];
  const float* whh1 = (const float*)d_in[6];
  const float* bih1 = (const float*)d_in[7];
  const float* bhh1 = (const float*)d_in[8];
  const float* wih2 = (const float*)d_in[9];
  const float* whh2 = (const float*)d_in[10];
  const float* bih2 = (const float*)d_in[11];
  const float* bhh2 = (const float*)d_in[12];
  const float* wout = (const float*)d_in[13];
  const float* bout = (const float*)d_in[14];
  float* out = (float*)d_out;

  rnn3_fused<<<dim3(NBAT / 16), dim3(64), 0, stream>>>(
      x, wih0, whh0, bih0, bhh0, wih1, whh1, bih1, bhh1,
      wih2, whh2, bih2, bhh2, wout, bout, out);
}

// Round 5
// 232.369 us; speedup vs baseline: 1.1454x; 1.1454x over previous
//
#include <hip/hip_runtime.h>
#include <hip/hip_fp16.h>

// Fused 3-layer ReLU-RNN + linear head, MI355X (gfx950).
// T=512, B=4096, IN=4, H1=24, H2=48, H3=24, OUT=2.
//
// One wave owns 16 batch columns for the whole recurrence (batch = MFMA N,
// neurons = M). Weights live in VGPRs as A-fragments; biases ride as MFMA C.
//
// ROUND 5: round-4 structure (layer-skewed pipeline, MFMA-first / pack-last,
// sched_barrier(0) boundary) with the pack path reverted to PURE INTRINSICS
// (fmaxf in f32 + __floats2half2_rn), matching rounds 1-2 bit-for-bit.
// Round 4's inline-asm v_pk_max_f16 fed MFMA B-operands from an asm VALU
// write — hipcc's hazard/scheduling handling of inline asm around MFMA is
// unreliable (guide rule #18) and produced moderate data-dependent
// corruption. No asm anywhere in this kernel.
//
// Iteration i issues MFMAs for L0(i), L1(i-1), L2(i-2), out(i-3) using
// B-fragments packed at the END of iteration i-1; packs at the bottom of
// iteration i read this iteration's accumulators oldest-first, so every MFMA
// result is ~100+ cycles old when the VALU touches it (with one wave/SIMD,
// any MFMA->VALU hazard wait is pure dead time — round 2 proved that
// concentrating reads near writes is catastrophic).

#define TSEQ 512
#define NBAT 4096

typedef float    f32x4 __attribute__((ext_vector_type(4)));
typedef _Float16 f16x8 __attribute__((ext_vector_type(8)));

union BFrag { f16x8 h; unsigned u[4]; };

__device__ __forceinline__ f32x4 MF(f16x8 a, f16x8 b, f32x4 c) {
  return __builtin_amdgcn_mfma_f32_16x16x32_f16(a, b, c, 0, 0, 0);
}

__device__ __forceinline__ unsigned pkh(float a, float b) {
  union { __half2 h2; unsigned u; } x;
  x.h2 = __floats2half2_rn(a, b);
  return x.u;
}
// relu in f32, then pack (identical to rounds 1-2; pure intrinsics).
__device__ __forceinline__ unsigned pkr(float a, float b) {
  return pkh(fmaxf(a, 0.f), fmaxf(b, 0.f));
}

struct WP {
  const float *wih0, *whh0, *wih1, *whh1, *wih2, *whh2, *wout;
};

// Concatenated-weight view per layer, zero-padded so garbage B slots
// always multiply by 0.
//  L0 (K=32): k<24 -> W_hh0[m][k] (h1_prev), k in [28,32) -> W_ih0[m][k-28] (x_t)
//  L1 (K=96): k<24 -> W_ih1[m][k] (a1),     k in [32,80) -> W_hh1[m][k-32] (h2_prev)
//  L2 (K=96): k<48 -> W_ih2[m][k] (a2),     k in [48,72) -> W_hh2[m][k-48] (h3_prev)
//  L3 (K=32): k<24 -> W_out[m][k] (a3), m<2
__device__ float wcat(int layer, int m, int k, const WP& P) {
  if (layer == 0) {
    if (m < 24) {
      if (k < 24) return P.whh0[m * 24 + k];
      if (k >= 28 && k < 32) return P.wih0[m * 4 + (k - 28)];
    }
    return 0.f;
  } else if (layer == 1) {
    if (m < 48) {
      if (k < 24) return P.wih1[m * 24 + k];
      if (k >= 32 && k < 80) return P.whh1[m * 48 + (k - 32)];
    }
    return 0.f;
  } else if (layer == 2) {
    if (m < 24) {
      if (k < 48) return P.wih2[m * 48 + k];
      if (k >= 48 && k < 72) return P.whh2[m * 24 + (k - 48)];
    }
    return 0.f;
  } else {
    if (m < 2 && k < 24) return P.wout[m * 24 + k];
    return 0.f;
  }
}

// A fragment (16x16x32 f16): lane holds row m = 16*mt + (lane&15),
// slots j<4: k = kc*32 + 4q + j ; slots j>=4: k = kc*32 + 16 + 4q + (j-4).
__device__ f16x8 afrag(int layer, int mt, int kc, const WP& P) {
  int m  = mt * 16 + (threadIdx.x & 15);
  int kb = kc * 32 + 4 * ((threadIdx.x >> 4) & 3);
  f16x8 r;
#pragma unroll
  for (int j = 0; j < 4; ++j) r[j] = (_Float16)wcat(layer, m, kb + j, P);
#pragma unroll
  for (int j = 0; j < 4; ++j) r[4 + j] = (_Float16)wcat(layer, m, kb + 16 + j, P);
  return r;
}

// Bias as C operand: reg i holds bias for neuron m = 16*mt + 4q + i.
__device__ f32x4 cfrag(const float* b1, const float* b2, int mt, int nvalid) {
  int qq = (threadIdx.x >> 4) & 3;
  f32x4 r;
#pragma unroll
  for (int i = 0; i < 4; ++i) {
    int m = mt * 16 + 4 * qq + i;
    float v = 0.f;
    if (m < nvalid) { v = b1[m]; if (b2) v += b2[m]; }
    r[i] = v;
  }
  return r;
}

// One pipeline iteration.  ST: store y(I-4).  ZH2: zero h2 pack (I==0).
// ZH3: zero h3 pack (I<2).
#define BODY(I, ST, ZH2, ZH3)                                                  \
  do {                                                                         \
    /* aged out-store: ao holds y((I)-4), written by iter (I)-1 */             \
    if (ST) {                                                                  \
      if (q == 0)                                                              \
        o2[(size_t)((I) - 4) * NBAT + b0 + c] = make_float2(ao[0], ao[1]);     \
    }                                                                          \
    /* assemble B operands from last iteration's packed regs */                \
    BFrag FA, FB, FC, FD, BE;                                                  \
    FA.u[0] = fa0; FA.u[1] = fa1; FA.u[2] = fa2; FA.u[3] = fa3;                \
    FB.u[0] = fb0; FB.u[1] = fb1; FB.u[2] = fb2; FB.u[3] = fb3;                \
    FC.u[0] = fc0; FC.u[1] = fc1; FC.u[2] = fd0; FC.u[3] = fd1;                \
    BE.u[0] = fd2; BE.u[1] = fd3; BE.u[2] = 0u; BE.u[3] = 0u;                  \
    FD.u[0] = fd0; FD.u[1] = fd1; FD.u[2] = fd2; FD.u[3] = fd3;                \
    /* ---- MFMA phase: L0(I), L1(I-1), L2(I-2), out(I-3) ---- */              \
    a10 = MF(A00, FA.h, C00);                                                  \
    a11 = MF(A01, FA.h, C01);                                                  \
    a20 = MF(A1[0][0], FA.h, C10);                                             \
    a21 = MF(A1[1][0], FA.h, C11);                                             \
    a22 = MF(A1[2][0], FA.h, C12);                                             \
    a20 = MF(A1[0][1], FB.h, a20);                                             \
    a21 = MF(A1[1][1], FB.h, a21);                                             \
    a22 = MF(A1[2][1], FB.h, a22);                                             \
    a20 = MF(A1[0][2], FC.h, a20);                                             \
    a21 = MF(A1[1][2], FC.h, a21);                                             \
    a22 = MF(A1[2][2], FC.h, a22);                                             \
    a30 = MF(A2[0][0], FB.h, C20);                                             \
    a31 = MF(A2[1][0], FB.h, C21);                                             \
    a30 = MF(A2[0][1], FC.h, a30);                                             \
    a31 = MF(A2[1][1], FC.h, a31);                                             \
    a30 = MF(A2[0][2], BE.h, a30);                                             \
    a31 = MF(A2[1][2], BE.h, a31);                                             \
    ao  = MF(A3, FD.h, C3);                                                    \
    /* x prefetch for step (I)+3 (consumed 3 iterations from now) */           \
    {                                                                          \
      int tn = (I) + 3 < TSEQ ? (I) + 3 : TSEQ - 1;                            \
      xn = x4[(size_t)tn * NBAT + b0 + c];                                     \
    }                                                                          \
    __builtin_amdgcn_sched_barrier(0);                                         \
    /* ---- pack phase (reads accs oldest-first) -> next iter's B regs ---- */ \
    fa0 = pkr(a10[0], a10[1]); fa1 = pkr(a10[2], a10[3]);                      \
    {                                                                          \
      unsigned h1b = pkr(a11[0], a11[1]), h1c = pkr(a11[2], a11[3]);           \
      fa2 = (q == 3) ? pkh(xcur.x, xcur.y) : h1b;                              \
      fa3 = (q == 3) ? pkh(xcur.z, xcur.w) : h1c;                              \
    }                                                                          \
    fb0 = pkr(a20[0], a20[1]); fb1 = pkr(a20[2], a20[3]);                      \
    fb2 = pkr(a21[0], a21[1]); fb3 = pkr(a21[2], a21[3]);                      \
    fc0 = pkr(a22[0], a22[1]); fc1 = pkr(a22[2], a22[3]);                      \
    if (ZH2) { fb0 = fb1 = fb2 = fb3 = fc0 = fc1 = 0u; }                       \
    fd0 = pkr(a30[0], a30[1]); fd1 = pkr(a30[2], a30[3]);                      \
    fd2 = pkr(a31[0], a31[1]); fd3 = pkr(a31[2], a31[3]);                      \
    if (ZH3) { fd0 = fd1 = fd2 = fd3 = 0u; }                                   \
    xcur = xnxt; xnxt = xn;                                                    \
  } while (0)

__global__ void __launch_bounds__(64)
rnn3_fused(const float* __restrict__ x,
           const float* __restrict__ wih0, const float* __restrict__ whh0,
           const float* __restrict__ bih0, const float* __restrict__ bhh0,
           const float* __restrict__ wih1, const float* __restrict__ whh1,
           const float* __restrict__ bih1, const float* __restrict__ bhh1,
           const float* __restrict__ wih2, const float* __restrict__ whh2,
           const float* __restrict__ bih2, const float* __restrict__ bhh2,
           const float* __restrict__ wout, const float* __restrict__ bout,
           float* __restrict__ out) {
  const int lane = threadIdx.x;
  const int c = lane & 15;
  const int q = lane >> 4;
  const int b0 = blockIdx.x * 16;

  WP P{wih0, whh0, wih1, whh1, wih2, whh2, wout};

  // persistent weight fragments
  f16x8 A00 = afrag(0, 0, 0, P);
  f16x8 A01 = afrag(0, 1, 0, P);
  f16x8 A1[3][3];
#pragma unroll
  for (int mt = 0; mt < 3; ++mt)
#pragma unroll
    for (int kc = 0; kc < 3; ++kc) A1[mt][kc] = afrag(1, mt, kc, P);
  f16x8 A2[2][3];
#pragma unroll
  for (int mt = 0; mt < 2; ++mt)
#pragma unroll
    for (int kc = 0; kc < 3; ++kc) A2[mt][kc] = afrag(2, mt, kc, P);
  f16x8 A3 = afrag(3, 0, 0, P);

  // bias fragments
  f32x4 C00 = cfrag(bih0, bhh0, 0, 24);
  f32x4 C01 = cfrag(bih0, bhh0, 1, 24);
  f32x4 C10 = cfrag(bih1, bhh1, 0, 48);
  f32x4 C11 = cfrag(bih1, bhh1, 1, 48);
  f32x4 C12 = cfrag(bih1, bhh1, 2, 48);
  f32x4 C20 = cfrag(bih2, bhh2, 0, 24);
  f32x4 C21 = cfrag(bih2, bhh2, 1, 24);
  f32x4 C3  = cfrag(bout, nullptr, 0, 2);

  const float4* x4 = (const float4*)x;
  float2*       o2 = (float2*)out;

  // accumulators (MFMA writes at top of iter, packs read at bottom)
  f32x4 a10{}, a11{}, a20{}, a21{}, a22{}, a30{}, a31{}, ao{};

  // packed B-operand registers
  unsigned fa0, fa1, fa2, fa3;      // [h1(prev) | x(cur) in q3]
  unsigned fb0, fb1, fb2, fb3;      // h2(prev) tiles 0,1
  unsigned fc0, fc1;                // h2(prev) tile 2
  unsigned fd0, fd1, fd2, fd3;      // h3(prev) tiles 0,1

  // init: iteration 0's FA = [h1(-1)=0 | x(0)]
  {
    float4 xv0 = x4[(size_t)b0 + c];
    fa0 = fa1 = 0u;
    fa2 = (q == 3) ? pkh(xv0.x, xv0.y) : 0u;
    fa3 = (q == 3) ? pkh(xv0.z, xv0.w) : 0u;
  }
  fb0 = fb1 = fb2 = fb3 = fc0 = fc1 = 0u;
  fd0 = fd1 = fd2 = fd3 = 0u;

  float4 xcur = x4[(size_t)1 * NBAT + b0 + c];  // x(1)
  float4 xnxt = x4[(size_t)2 * NBAT + b0 + c];  // x(2)
  float4 xn;

  // ---- pipeline fill (no stores; zero invalid recurrence packs) ----
  BODY(0, 0, 1, 1);
  BODY(1, 0, 0, 1);
  BODY(2, 0, 0, 0);
  BODY(3, 0, 0, 0);

  // ---- steady state + drain: stores y(0..TSEQ-1) ----
#pragma unroll 1
  for (int i = 4; i < TSEQ + 4; ++i) {
    BODY(i, 1, 0, 0);
  }
}

extern "C" void kernel_launch(void* const* d_in, const int* in_sizes, int n_in,
                              void* d_out, int out_size, void* d_ws, size_t ws_size,
                              hipStream_t stream) {
  const float* x    = (const float*)d_in[0];
  const float* wih0 = (const float*)d_in[1];
  const float* whh0 = (const float*)d_in[2];
  const float* bih0 = (const float*)d_in[3];
  const float* bhh0 = (const float*)d_in[4];
  const float* wih1 = (const float*)d_in[5];
  const float* whh1 = (const float*)d_in[6];
  const float* bih1 = (const float*)d_in[7];
  const float* bhh1 = (const float*)d_in[8];
  const float* wih2 = (const float*)d_in[9];
  const float* whh2 = (const float*)d_in[10];
  const float* bih2 = (const float*)d_in[11];
  const float* bhh2 = (const float*)d_in[12];
  const float* wout = (const float*)d_in[13];
  const float* bout = (const float*)d_in[14];
  float* out = (float*)d_out;

  rnn3_fused<<<dim3(NBAT / 16), dim3(64), 0, stream>>>(
      x, wih0, whh0, bih0, bhh0, wih1, whh1, bih1, bhh1,
      wih2, whh2, bih2, bhh2, wout, bout, out);
}

// Round 6
// 193.708 us; speedup vs baseline: 1.3740x; 1.1996x over previous
//
#include <hip/hip_runtime.h>
#include <hip/hip_fp16.h>

// Fused 3-layer ReLU-RNN + linear head, MI355X (gfx950).
// T=512, B=4096, IN=4, H1=24, H2=48, H3=24, OUT=2.
//
// One wave owns 16 batch columns for the whole recurrence (batch = MFMA N,
// neurons = M). Weights live in VGPRs as A-fragments; biases ride as MFMA C.
// Layer-skewed pipeline: iteration i issues L0(i), L1(i-1), L2(i-2), out(i-3).
//
// ROUND 6: kill the per-step VMEM drain. Rounds 1/2/5 all rotated the x
// prefetch through xcur/xnxt register moves inside a non-unrolled loop, which
// forces s_waitcnt on the SAME-iteration load (plus the store ahead of it in
// program order -> effectively vmcnt(0) + full HBM latency ~500-900 cyc every
// step = the ~800 idle cycles rocprof showed). Now: 8-deep x ring with
// compile-time slot indices (steady loop unrolled x8; i = 4 mod 8 so
// (i+j)&7 is a constant per body). A load issued at body i is consumed at
// body i+8 (~2000 cycles later) - latency fully covered, counted vmcnt waits.
// MFMA issue order interleaves the three chained-accumulator groups so
// same-acc MFMAs are >=5 issue slots apart. Packs stay pure intrinsics
// (round 4 proved inline-asm VALU feeding MFMA operands corrupts).

#define TSEQ 512
#define NBAT 4096

typedef float    f32x4 __attribute__((ext_vector_type(4)));
typedef _Float16 f16x8 __attribute__((ext_vector_type(8)));

union BFrag { f16x8 h; unsigned u[4]; };

__device__ __forceinline__ f32x4 MF(f16x8 a, f16x8 b, f32x4 c) {
  return __builtin_amdgcn_mfma_f32_16x16x32_f16(a, b, c, 0, 0, 0);
}

__device__ __forceinline__ unsigned pkh(float a, float b) {
  union { __half2 h2; unsigned u; } x;
  x.h2 = __floats2half2_rn(a, b);
  return x.u;
}
// relu in f32, then pack (pure intrinsics).
__device__ __forceinline__ unsigned pkr(float a, float b) {
  return pkh(fmaxf(a, 0.f), fmaxf(b, 0.f));
}

struct WP {
  const float *wih0, *whh0, *wih1, *whh1, *wih2, *whh2, *wout;
};

// Concatenated-weight view per layer, zero-padded so garbage B slots
// always multiply by 0.
//  L0 (K=32): k<24 -> W_hh0[m][k] (h1_prev), k in [28,32) -> W_ih0[m][k-28] (x_t)
//  L1 (K=96): k<24 -> W_ih1[m][k] (a1),     k in [32,80) -> W_hh1[m][k-32] (h2_prev)
//  L2 (K=96): k<48 -> W_ih2[m][k] (a2),     k in [48,72) -> W_hh2[m][k-48] (h3_prev)
//  L3 (K=32): k<24 -> W_out[m][k] (a3), m<2
__device__ float wcat(int layer, int m, int k, const WP& P) {
  if (layer == 0) {
    if (m < 24) {
      if (k < 24) return P.whh0[m * 24 + k];
      if (k >= 28 && k < 32) return P.wih0[m * 4 + (k - 28)];
    }
    return 0.f;
  } else if (layer == 1) {
    if (m < 48) {
      if (k < 24) return P.wih1[m * 24 + k];
      if (k >= 32 && k < 80) return P.whh1[m * 48 + (k - 32)];
    }
    return 0.f;
  } else if (layer == 2) {
    if (m < 24) {
      if (k < 48) return P.wih2[m * 48 + k];
      if (k >= 48 && k < 72) return P.whh2[m * 24 + (k - 48)];
    }
    return 0.f;
  } else {
    if (m < 2 && k < 24) return P.wout[m * 24 + k];
    return 0.f;
  }
}

// A fragment (16x16x32 f16): lane holds row m = 16*mt + (lane&15),
// slots j<4: k = kc*32 + 4q + j ; slots j>=4: k = kc*32 + 16 + 4q + (j-4).
__device__ f16x8 afrag(int layer, int mt, int kc, const WP& P) {
  int m  = mt * 16 + (threadIdx.x & 15);
  int kb = kc * 32 + 4 * ((threadIdx.x >> 4) & 3);
  f16x8 r;
#pragma unroll
  for (int j = 0; j < 4; ++j) r[j] = (_Float16)wcat(layer, m, kb + j, P);
#pragma unroll
  for (int j = 0; j < 4; ++j) r[4 + j] = (_Float16)wcat(layer, m, kb + 16 + j, P);
  return r;
}

// Bias as C operand: reg i holds bias for neuron m = 16*mt + 4q + i.
__device__ f32x4 cfrag(const float* b1, const float* b2, int mt, int nvalid) {
  int qq = (threadIdx.x >> 4) & 3;
  f32x4 r;
#pragma unroll
  for (int i = 0; i < 4; ++i) {
    int m = mt * 16 + 4 * qq + i;
    float v = 0.f;
    if (m < nvalid) { v = b1[m]; if (b2) v += b2[m]; }
    r[i] = v;
  }
  return r;
}

// One pipeline iteration. I: step index (compile-time-constant expression in
// the unrolled loop bodies below). SLOT: x-ring slot (compile-time constant).
// ST: store y(I-4).  ZH2: zero h2 pack (I==0).  ZH3: zero h3 pack (I<2).
#define BODY(I, SLOT, ST, ZH2, ZH3)                                            \
  do {                                                                         \
    /* aged out-store: ao holds y((I)-4), written by iter (I)-1 */             \
    if (ST) {                                                                  \
      if (q == 0)                                                              \
        o2[(size_t)((I) - 4) * NBAT + b0 + c] = make_float2(ao[0], ao[1]);     \
    }                                                                          \
    /* assemble B operands from last iteration's packed regs */                \
    BFrag FA, FB, FC, FD, BE;                                                  \
    FA.u[0] = fa0; FA.u[1] = fa1; FA.u[2] = fa2; FA.u[3] = fa3;                \
    FB.u[0] = fb0; FB.u[1] = fb1; FB.u[2] = fb2; FB.u[3] = fb3;                \
    FC.u[0] = fc0; FC.u[1] = fc1; FC.u[2] = fd0; FC.u[3] = fd1;                \
    BE.u[0] = fd2; BE.u[1] = fd3; BE.u[2] = 0u; BE.u[3] = 0u;                  \
    FD.u[0] = fd0; FD.u[1] = fd1; FD.u[2] = fd2; FD.u[3] = fd3;                \
    /* ---- MFMA phase: L0(I), L1(I-1), L2(I-2), out(I-3) ----                 \
       chained accumulators (a2x over 3 chunks, a3x over 3 chunks) are        \
       interleaved so same-acc MFMAs sit >=5 issue slots apart */             \
    a10 = MF(A00, FA.h, C00);                                                  \
    a11 = MF(A01, FA.h, C01);                                                  \
    a20 = MF(A1[0][0], FA.h, C10);                                             \
    a21 = MF(A1[1][0], FA.h, C11);                                             \
    a22 = MF(A1[2][0], FA.h, C12);                                             \
    a30 = MF(A2[0][0], FB.h, C20);                                             \
    a31 = MF(A2[1][0], FB.h, C21);                                             \
    a20 = MF(A1[0][1], FB.h, a20);                                             \
    a21 = MF(A1[1][1], FB.h, a21);                                             \
    a22 = MF(A1[2][1], FB.h, a22);                                             \
    a30 = MF(A2[0][1], FC.h, a30);                                             \
    a31 = MF(A2[1][1], FC.h, a31);                                             \
    a20 = MF(A1[0][2], FC.h, a20);                                             \
    a21 = MF(A1[1][2], FC.h, a21);                                             \
    a22 = MF(A1[2][2], FC.h, a22);                                             \
    a30 = MF(A2[0][2], BE.h, a30);                                             \
    a31 = MF(A2[1][2], BE.h, a31);                                             \
    ao  = MF(A3, FD.h, C3);                                                    \
    __builtin_amdgcn_sched_barrier(0);                                         \
    /* ---- pack phase -> next iter's B regs ---- */                           \
    /* x(I+1) from the ring (loaded 8 iterations ago) */                       \
    {                                                                          \
      unsigned xlo = pkh(xb[SLOT].x, xb[SLOT].y);                              \
      unsigned xhi = pkh(xb[SLOT].z, xb[SLOT].w);                              \
      fa0 = pkr(a10[0], a10[1]); fa1 = pkr(a10[2], a10[3]);                    \
      unsigned h1b = pkr(a11[0], a11[1]), h1c = pkr(a11[2], a11[3]);           \
      fa2 = (q == 3) ? xlo : h1b;                                              \
      fa3 = (q == 3) ? xhi : h1c;                                              \
    }                                                                          \
    /* refill the slot with x(I+9) (consumed 8 iterations from now) */         \
    {                                                                          \
      int tn = (I) + 9 < TSEQ ? (I) + 9 : TSEQ - 1;                            \
      xb[SLOT] = x4[(size_t)tn * NBAT + b0 + c];                               \
    }                                                                          \
    fb0 = pkr(a20[0], a20[1]); fb1 = pkr(a20[2], a20[3]);                      \
    fb2 = pkr(a21[0], a21[1]); fb3 = pkr(a21[2], a21[3]);                      \
    fc0 = pkr(a22[0], a22[1]); fc1 = pkr(a22[2], a22[3]);                      \
    if (ZH2) { fb0 = fb1 = fb2 = fb3 = fc0 = fc1 = 0u; }                       \
    fd0 = pkr(a30[0], a30[1]); fd1 = pkr(a30[2], a30[3]);                      \
    fd2 = pkr(a31[0], a31[1]); fd3 = pkr(a31[2], a31[3]);                      \
    if (ZH3) { fd0 = fd1 = fd2 = fd3 = 0u; }                                   \
  } while (0)

__global__ void __launch_bounds__(64)
rnn3_fused(const float* __restrict__ x,
           const float* __restrict__ wih0, const float* __restrict__ whh0,
           const float* __restrict__ bih0, const float* __restrict__ bhh0,
           const float* __restrict__ wih1, const float* __restrict__ whh1,
           const float* __restrict__ bih1, const float* __restrict__ bhh1,
           const float* __restrict__ wih2, const float* __restrict__ whh2,
           const float* __restrict__ bih2, const float* __restrict__ bhh2,
           const float* __restrict__ wout, const float* __restrict__ bout,
           float* __restrict__ out) {
  const int lane = threadIdx.x;
  const int c = lane & 15;
  const int q = lane >> 4;
  const int b0 = blockIdx.x * 16;

  WP P{wih0, whh0, wih1, whh1, wih2, whh2, wout};

  const float4* x4 = (const float4*)x;
  float2*       o2 = (float2*)out;

  // ---- x prefetch ring: xb[j] holds x(i+1+((j-i)&7)) ... i.e. at the top of
  // iteration i, slot (i&7) holds x(i+1). Init: xb[j] = x(1+j). ----
  float4 xb[8];
#pragma unroll
  for (int j = 0; j < 8; ++j) {
    int tj = 1 + j < TSEQ ? 1 + j : TSEQ - 1;
    xb[j] = x4[(size_t)tj * NBAT + b0 + c];
  }
  float4 xv0 = x4[(size_t)b0 + c];  // x(0) for iteration 0's FA

  // persistent weight fragments
  f16x8 A00 = afrag(0, 0, 0, P);
  f16x8 A01 = afrag(0, 1, 0, P);
  f16x8 A1[3][3];
#pragma unroll
  for (int mt = 0; mt < 3; ++mt)
#pragma unroll
    for (int kc = 0; kc < 3; ++kc) A1[mt][kc] = afrag(1, mt, kc, P);
  f16x8 A2[2][3];
#pragma unroll
  for (int mt = 0; mt < 2; ++mt)
#pragma unroll
    for (int kc = 0; kc < 3; ++kc) A2[mt][kc] = afrag(2, mt, kc, P);
  f16x8 A3 = afrag(3, 0, 0, P);

  // bias fragments
  f32x4 C00 = cfrag(bih0, bhh0, 0, 24);
  f32x4 C01 = cfrag(bih0, bhh0, 1, 24);
  f32x4 C10 = cfrag(bih1, bhh1, 0, 48);
  f32x4 C11 = cfrag(bih1, bhh1, 1, 48);
  f32x4 C12 = cfrag(bih1, bhh1, 2, 48);
  f32x4 C20 = cfrag(bih2, bhh2, 0, 24);
  f32x4 C21 = cfrag(bih2, bhh2, 1, 24);
  f32x4 C3  = cfrag(bout, nullptr, 0, 2);

  // accumulators (MFMA writes at top of iter, packs read at bottom)
  f32x4 a10{}, a11{}, a20{}, a21{}, a22{}, a30{}, a31{}, ao{};

  // packed B-operand registers
  unsigned fa0, fa1, fa2, fa3;      // [h1(prev) | x(cur) in q3]
  unsigned fb0, fb1, fb2, fb3;      // h2(prev) tiles 0,1
  unsigned fc0, fc1;                // h2(prev) tile 2
  unsigned fd0, fd1, fd2, fd3;      // h3(prev) tiles 0,1

  // init: iteration 0's FA = [h1(-1)=0 | x(0)]
  fa0 = fa1 = 0u;
  fa2 = (q == 3) ? pkh(xv0.x, xv0.y) : 0u;
  fa3 = (q == 3) ? pkh(xv0.z, xv0.w) : 0u;
  fb0 = fb1 = fb2 = fb3 = fc0 = fc1 = 0u;
  fd0 = fd1 = fd2 = fd3 = 0u;

  // ---- pipeline fill: iterations 0..3 (no stores; zero invalid packs) ----
  BODY(0, 0, 0, 1, 1);
  BODY(1, 1, 0, 0, 1);
  BODY(2, 2, 0, 0, 0);
  BODY(3, 3, 0, 0, 0);

  // ---- steady state + drain: i = 4..515, stores y(0..511).
  // i = 4 (mod 8) every loop iteration, so slot (i+j)&7 is compile-time. ----
#pragma unroll 1
  for (int i = 4; i < TSEQ + 4; i += 8) {
    BODY(i + 0, 4, 1, 0, 0);
    BODY(i + 1, 5, 1, 0, 0);
    BODY(i + 2, 6, 1, 0, 0);
    BODY(i + 3, 7, 1, 0, 0);
    BODY(i + 4, 0, 1, 0, 0);
    BODY(i + 5, 1, 1, 0, 0);
    BODY(i + 6, 2, 1, 0, 0);
    BODY(i + 7, 3, 1, 0, 0);
  }
}

extern "C" void kernel_launch(void* const* d_in, const int* in_sizes, int n_in,
                              void* d_out, int out_size, void* d_ws, size_t ws_size,
                              hipStream_t stream) {
  const float* x    = (const float*)d_in[0];
  const float* wih0 = (const float*)d_in[1];
  const float* whh0 = (const float*)d_in[2];
  const float* bih0 = (const float*)d_in[3];
  const float* bhh0 = (const float*)d_in[4];
  const float* wih1 = (const float*)d_in[5];
  const float* whh1 = (const float*)d_in[6];
  const float* bih1 = (const float*)d_in[7];
  const float* bhh1 = (const float*)d_in[8];
  const float* wih2 = (const float*)d_in[9];
  const float* whh2 = (const float*)d_in[10];
  const float* bih2 = (const float*)d_in[11];
  const float* bhh2 = (const float*)d_in[12];
  const float* wout = (const float*)d_in[13];
  const float* bout = (const float*)d_in[14];
  float* out = (float*)d_out;

  rnn3_fused<<<dim3(NBAT / 16), dim3(64), 0, stream>>>(
      x, wih0, whh0, bih0, bhh0, wih1, whh1, bih1, bhh1,
      wih2, whh2, bih2, bhh2, wout, bout, out);
}

// Round 7
// 103.914 us; speedup vs baseline: 2.5614x; 1.8641x over previous
//
#include <hip/hip_runtime.h>
#include <hip/hip_fp16.h>

// Fused 3-layer ReLU-RNN + linear head, MI355X (gfx950).
// T=512, B=4096, IN=4, H1=24, H2=48, H3=24, OUT=2.
//
// ROUND 7: 4-wave layer-pipelined block. One block (256 thr) per CU owns one
// 16-batch-column tile; the 18 MFMAs/step are split across the CU's 4 SIMD
// matrix pipes (per-SIMD 16x16x32 throughput ~15.5 cyc => 18 serial MFMAs on
// one SIMD ~280 cyc was the real bottleneck, not hazards):
//   w0: L0(i) + out(i-8) + store   (3 MFMA)
//   w1: L1 mt0,mt1 (i-3)           (6 MFMA)
//   w2: L1 mt2 (i-3) + L2 mt1 (i-6)(6 MFMA)
//   w3: L2 mt0 (i-6)               (3 MFMA)
// Self-recurrences stay in-register in the owning wave; cross-wave feeds go
// through a 4-slot LDS ring. >=2-step-old data is pre-read one iteration
// early (latency hidden); 1-step edges are read at top-of-iteration and
// consumed by the last MFMAs. Barrier = counted lgkmcnt + raw s_barrier
// (writes issued before pre-reads; DS completes in order per wave), so w0's
// x prefetch ring / y stores never hit a vmcnt drain.

#define TSEQ 512
#define NBAT 4096

typedef float    f32x4 __attribute__((ext_vector_type(4)));
typedef _Float16 f16x8 __attribute__((ext_vector_type(8)));

union BFrag { f16x8 h; unsigned u[4]; };

__device__ __forceinline__ f32x4 MF(f16x8 a, f16x8 b, f32x4 c) {
  return __builtin_amdgcn_mfma_f32_16x16x32_f16(a, b, c, 0, 0, 0);
}

__device__ __forceinline__ unsigned pkh(float a, float b) {
  union { __half2 h2; unsigned u; } x;
  x.h2 = __floats2half2_rn(a, b);
  return x.u;
}
__device__ __forceinline__ unsigned pkr(float a, float b) {
  return pkh(fmaxf(a, 0.f), fmaxf(b, 0.f));
}

// wait lgkmcnt(n) only (vmcnt=63, expcnt=7): gfx9 encoding, bits[11:8]=n.
#define LGKM_WAIT(n) __builtin_amdgcn_s_waitcnt(0xC07F | ((n) << 8))
#define BAR(n)                                                                 \
  do {                                                                         \
    __builtin_amdgcn_sched_barrier(0);                                         \
    LGKM_WAIT(n);                                                              \
    __builtin_amdgcn_s_barrier();                                              \
    __builtin_amdgcn_sched_barrier(0);                                         \
  } while (0)

struct WP {
  const float *wih0, *whh0, *wih1, *whh1, *wih2, *whh2, *wout;
};

// Concatenated zero-padded weight views (same as rounds 1-6):
//  L0 (K=32): k<24 -> W_hh0[m][k], k in [28,32) -> W_ih0[m][k-28]
//  L1 (K=96): k<24 -> W_ih1[m][k], k in [32,80) -> W_hh1[m][k-32]
//  L2 (K=96): k<48 -> W_ih2[m][k], k in [48,72) -> W_hh2[m][k-48]
//  L3 (K=32): k<24 -> W_out[m][k], m<2
__device__ float wcat(int layer, int m, int k, const WP& P) {
  if (layer == 0) {
    if (m < 24) {
      if (k < 24) return P.whh0[m * 24 + k];
      if (k >= 28 && k < 32) return P.wih0[m * 4 + (k - 28)];
    }
    return 0.f;
  } else if (layer == 1) {
    if (m < 48) {
      if (k < 24) return P.wih1[m * 24 + k];
      if (k >= 32 && k < 80) return P.whh1[m * 48 + (k - 32)];
    }
    return 0.f;
  } else if (layer == 2) {
    if (m < 24) {
      if (k < 48) return P.wih2[m * 48 + k];
      if (k >= 48 && k < 72) return P.whh2[m * 24 + (k - 48)];
    }
    return 0.f;
  } else {
    if (m < 2 && k < 24) return P.wout[m * 24 + k];
    return 0.f;
  }
}

__device__ f16x8 afrag(int layer, int mt, int kc, const WP& P) {
  int m  = mt * 16 + (threadIdx.x & 15);
  int kb = kc * 32 + 4 * ((threadIdx.x >> 4) & 3);
  f16x8 r;
#pragma unroll
  for (int j = 0; j < 4; ++j) r[j] = (_Float16)wcat(layer, m, kb + j, P);
#pragma unroll
  for (int j = 0; j < 4; ++j) r[4 + j] = (_Float16)wcat(layer, m, kb + 16 + j, P);
  return r;
}

__device__ f32x4 cfrag(const float* b1, const float* b2, int mt, int nvalid) {
  int qq = (threadIdx.x >> 4) & 3;
  f32x4 r;
#pragma unroll
  for (int i = 0; i < 4; ++i) {
    int m = mt * 16 + 4 * qq + i;
    float v = 0.f;
    if (m < nvalid) { v = b1[m]; if (b2) v += b2[m]; }
    r[i] = v;
  }
  return r;
}

__global__ void __launch_bounds__(256)
rnn3_pipe(const float* __restrict__ x,
          const float* __restrict__ wih0, const float* __restrict__ whh0,
          const float* __restrict__ bih0, const float* __restrict__ bhh0,
          const float* __restrict__ wih1, const float* __restrict__ whh1,
          const float* __restrict__ bih1, const float* __restrict__ bhh1,
          const float* __restrict__ wih2, const float* __restrict__ whh2,
          const float* __restrict__ bih2, const float* __restrict__ bhh2,
          const float* __restrict__ wout, const float* __restrict__ bout,
          float* __restrict__ out) {
  // LDS ring: [slot][lane], slot keyed by STEP s&3 of the state it holds.
  __shared__ uint4 sH1[4][64];   // h1 frag (4dw)
  __shared__ uint4 sH2A[4][64];  // h2[0:32] (4dw)
  __shared__ uint2 sH2B[4][64];  // h2[32:48] (2dw)
  __shared__ uint2 sH3A[4][64];  // h3[0:16] (2dw)
  __shared__ uint2 sH3B[4][64];  // h3[16:24] (2dw)

  const int tid  = threadIdx.x;
  const int wid  = tid >> 6;
  const int lane = tid & 63;
  const int c = lane & 15;
  const int q = lane >> 4;
  const int b0 = blockIdx.x * 16;

  WP P{wih0, whh0, wih1, whh1, wih2, whh2, wout};
  const float4* x4 = (const float4*)x;
  float2*       o2 = (float2*)out;

  if (wid == 0) {
    // ================= wave 0: L0(i), out(i-8), store, x-ring =================
    f16x8 A00 = afrag(0, 0, 0, P), A01 = afrag(0, 1, 0, P), A3 = afrag(3, 0, 0, P);
    f32x4 C00 = cfrag(bih0, bhh0, 0, 24), C01 = cfrag(bih0, bhh0, 1, 24);
    f32x4 C3  = cfrag(bout, nullptr, 0, 2);

    float4 xb[8];
#pragma unroll
    for (int j = 0; j < 8; ++j) xb[j] = x4[(size_t)(1 + j) * NBAT + b0 + c];
    float4 xv0 = x4[(size_t)b0 + c];

    BFrag FA;
    FA.u[0] = 0u; FA.u[1] = 0u;
    FA.u[2] = (q == 3) ? pkh(xv0.x, xv0.y) : 0u;
    FA.u[3] = (q == 3) ? pkh(xv0.z, xv0.w) : 0u;
    uint2 fdp01 = make_uint2(0u, 0u), fdp23 = make_uint2(0u, 0u);
    f32x4 a10, a11, ao;

#define W0BODY(IEXPR, K, R, ST)                                                \
  do {                                                                         \
    BFrag FDu;                                                                 \
    FDu.u[0] = fdp01.x; FDu.u[1] = fdp01.y;                                    \
    FDu.u[2] = fdp23.x; FDu.u[3] = fdp23.y;                                    \
    a10 = MF(A00, FA.h, C00);                                                  \
    a11 = MF(A01, FA.h, C01);                                                  \
    ao  = MF(A3, FDu.h, C3);                                                   \
    __builtin_amdgcn_sched_barrier(0);                                         \
    unsigned p0 = pkr(a10[0], a10[1]), p1 = pkr(a10[2], a10[3]);               \
    unsigned p2 = pkr(a11[0], a11[1]), p3 = pkr(a11[2], a11[3]);               \
    sH1[K][lane] = make_uint4(p0, p1, p2, p3);                                 \
    int I_ = (IEXPR);                                                          \
    unsigned xlo = pkh(xb[R].x, xb[R].y), xhi = pkh(xb[R].z, xb[R].w);         \
    FA.u[0] = p0; FA.u[1] = p1;                                                \
    FA.u[2] = (q == 3) ? xlo : p2;                                             \
    FA.u[3] = (q == 3) ? xhi : p3;                                             \
    int tn = I_ + 9 < TSEQ ? I_ + 9 : TSEQ - 1;                                \
    xb[R] = x4[(size_t)tn * NBAT + b0 + c];                                    \
    if (ST && q == 0)                                                          \
      o2[(size_t)(I_ - 8) * NBAT + b0 + c] = make_float2(ao[0], ao[1]);        \
    __builtin_amdgcn_sched_barrier(0);                                         \
    fdp01 = sH3A[(K + 1) & 3][lane];                                           \
    fdp23 = sH3B[(K + 1) & 3][lane];                                           \
    BAR(2);                                                                    \
  } while (0)

    W0BODY(0, 0, 0, 0); W0BODY(1, 1, 1, 0); W0BODY(2, 2, 2, 0); W0BODY(3, 3, 3, 0);
    W0BODY(4, 0, 4, 0); W0BODY(5, 1, 5, 0); W0BODY(6, 2, 6, 0); W0BODY(7, 3, 7, 0);
#pragma unroll 1
    for (int i = 8; i < TSEQ + 8; i += 8) {
      W0BODY(i + 0, 0, 0, 1); W0BODY(i + 1, 1, 1, 1);
      W0BODY(i + 2, 2, 2, 1); W0BODY(i + 3, 3, 3, 1);
      W0BODY(i + 4, 0, 4, 1); W0BODY(i + 5, 1, 5, 1);
      W0BODY(i + 6, 2, 6, 1); W0BODY(i + 7, 3, 7, 1);
    }
#undef W0BODY

  } else if (wid == 1) {
    // ================= wave 1: L1 mt0,mt1 (i-3) -> h2a =================
    f16x8 A1w[2][3];
#pragma unroll
    for (int mt = 0; mt < 2; ++mt)
#pragma unroll
      for (int kc = 0; kc < 3; ++kc) A1w[mt][kc] = afrag(1, mt, kc, P);
    f32x4 C10 = cfrag(bih1, bhh1, 0, 48), C11 = cfrag(bih1, bhh1, 1, 48);

    unsigned fb0 = 0u, fb1 = 0u, fb2 = 0u, fb3 = 0u;  // own h2a(prev)
    uint4 FAp = make_uint4(0u, 0u, 0u, 0u);           // pre-read h1
    f32x4 a20, a21;

#define W1BODY(K, ZH2)                                                         \
  do {                                                                         \
    uint2 rFC = sH2B[K][lane]; /* h2b(I-4), 1-step */                          \
    BFrag FBu, FAu, FCu;                                                       \
    FBu.u[0] = fb0; FBu.u[1] = fb1; FBu.u[2] = fb2; FBu.u[3] = fb3;            \
    FAu.u[0] = FAp.x; FAu.u[1] = FAp.y; FAu.u[2] = FAp.z; FAu.u[3] = FAp.w;    \
    a20 = MF(A1w[0][1], FBu.h, C10);                                           \
    a21 = MF(A1w[1][1], FBu.h, C11);                                           \
    a20 = MF(A1w[0][0], FAu.h, a20);                                           \
    a21 = MF(A1w[1][0], FAu.h, a21);                                           \
    FCu.u[0] = rFC.x; FCu.u[1] = rFC.y; FCu.u[2] = 0u; FCu.u[3] = 0u;          \
    a20 = MF(A1w[0][2], FCu.h, a20);                                           \
    a21 = MF(A1w[1][2], FCu.h, a21);                                           \
    __builtin_amdgcn_sched_barrier(0);                                         \
    fb0 = pkr(a20[0], a20[1]); fb1 = pkr(a20[2], a20[3]);                      \
    fb2 = pkr(a21[0], a21[1]); fb3 = pkr(a21[2], a21[3]);                      \
    if (ZH2) { fb0 = fb1 = fb2 = fb3 = 0u; }                                   \
    sH2A[(K + 1) & 3][lane] = make_uint4(fb0, fb1, fb2, fb3);                  \
    __builtin_amdgcn_sched_barrier(0);                                         \
    FAp = sH1[(K + 2) & 3][lane]; /* h1(I-2) for next iter */                  \
    BAR(1);                                                                    \
  } while (0)

    W1BODY(0, 1); W1BODY(1, 1); W1BODY(2, 1); W1BODY(3, 0);
    W1BODY(0, 0); W1BODY(1, 0); W1BODY(2, 0); W1BODY(3, 0);
#pragma unroll 1
    for (int i = 8; i < TSEQ + 8; i += 4) {
      W1BODY(0, 0); W1BODY(1, 0); W1BODY(2, 0); W1BODY(3, 0);
    }
#undef W1BODY

  } else if (wid == 2) {
    // ============ wave 2: L1 mt2 (i-3) -> h2b ; L2 mt1 (i-6) -> h3b ============
    f16x8 A1w2[3], A2w[3];
#pragma unroll
    for (int kc = 0; kc < 3; ++kc) A1w2[kc] = afrag(1, 2, kc, P);
#pragma unroll
    for (int kc = 0; kc < 3; ++kc) A2w[kc] = afrag(2, 1, kc, P);
    f32x4 C12 = cfrag(bih1, bhh1, 2, 48), C21 = cfrag(bih2, bhh2, 1, 24);

    unsigned fc0 = 0u, fc1 = 0u;      // own h2b(prev)
    unsigned fd2 = 0u, fd3 = 0u;      // own h3b(prev)
    uint4 FAp   = make_uint4(0u, 0u, 0u, 0u);  // pre-read h1(I-3)
    uint4 FBL2p = make_uint4(0u, 0u, 0u, 0u);  // pre-read h2a(I-6)
    uint2 h2bp  = make_uint2(0u, 0u);          // pre-read h2b(I-6)
    f32x4 a22, a31;

#define W2BODY(K, ZH2, ZH3)                                                    \
  do {                                                                         \
    uint4 rFB  = sH2A[K][lane];           /* h2a(I-4), 1-step */               \
    uint2 rH3A = sH3A[(K + 1) & 3][lane]; /* h3a(I-7), 1-step */               \
    BFrag FAu, FC2u, FBL2u, BE3u, FBu, FCL2u;                                  \
    FAu.u[0] = FAp.x; FAu.u[1] = FAp.y; FAu.u[2] = FAp.z; FAu.u[3] = FAp.w;    \
    FC2u.u[0] = fc0; FC2u.u[1] = fc1; FC2u.u[2] = 0u; FC2u.u[3] = 0u;          \
    FBL2u.u[0] = FBL2p.x; FBL2u.u[1] = FBL2p.y;                                \
    FBL2u.u[2] = FBL2p.z; FBL2u.u[3] = FBL2p.w;                                \
    BE3u.u[0] = fd2; BE3u.u[1] = fd3; BE3u.u[2] = 0u; BE3u.u[3] = 0u;          \
    a22 = MF(A1w2[0], FAu.h, C12);                                             \
    a31 = MF(A2w[0], FBL2u.h, C21);                                            \
    a22 = MF(A1w2[2], FC2u.h, a22);                                            \
    a31 = MF(A2w[2], BE3u.h, a31);                                             \
    FBu.u[0] = rFB.x; FBu.u[1] = rFB.y; FBu.u[2] = rFB.z; FBu.u[3] = rFB.w;    \
    a22 = MF(A1w2[1], FBu.h, a22);                                             \
    FCL2u.u[0] = h2bp.x; FCL2u.u[1] = h2bp.y;                                  \
    FCL2u.u[2] = rH3A.x; FCL2u.u[3] = rH3A.y;                                  \
    a31 = MF(A2w[1], FCL2u.h, a31);                                            \
    __builtin_amdgcn_sched_barrier(0);                                         \
    fc0 = pkr(a22[0], a22[1]); fc1 = pkr(a22[2], a22[3]);                      \
    if (ZH2) { fc0 = fc1 = 0u; }                                               \
    fd2 = pkr(a31[0], a31[1]); fd3 = pkr(a31[2], a31[3]);                      \
    if (ZH3) { fd2 = fd3 = 0u; }                                               \
    sH2B[(K + 1) & 3][lane] = make_uint2(fc0, fc1);                            \
    sH3B[(K + 2) & 3][lane] = make_uint2(fd2, fd3);                            \
    __builtin_amdgcn_sched_barrier(0);                                         \
    FAp   = sH1[(K + 2) & 3][lane];                                            \
    FBL2p = sH2A[(K + 3) & 3][lane];                                           \
    h2bp  = sH2B[(K + 3) & 3][lane];                                           \
    BAR(3);                                                                    \
  } while (0)

    W2BODY(0, 1, 1); W2BODY(1, 1, 1); W2BODY(2, 1, 1); W2BODY(3, 0, 1);
    W2BODY(0, 0, 1); W2BODY(1, 0, 1); W2BODY(2, 0, 0); W2BODY(3, 0, 0);
#pragma unroll 1
    for (int i = 8; i < TSEQ + 8; i += 4) {
      W2BODY(0, 0, 0); W2BODY(1, 0, 0); W2BODY(2, 0, 0); W2BODY(3, 0, 0);
    }
#undef W2BODY

  } else {
    // ================= wave 3: L2 mt0 (i-6) -> h3a =================
    f16x8 A2w0[3];
#pragma unroll
    for (int kc = 0; kc < 3; ++kc) A2w0[kc] = afrag(2, 0, kc, P);
    f32x4 C20 = cfrag(bih2, bhh2, 0, 24);

    unsigned fd0 = 0u, fd1 = 0u;               // own h3a(prev)
    uint4 FBL2p = make_uint4(0u, 0u, 0u, 0u);  // pre-read h2a(I-6)
    uint2 h2bp  = make_uint2(0u, 0u);          // pre-read h2b(I-6)
    f32x4 a30;

#define W3BODY(K, ZH3)                                                         \
  do {                                                                         \
    uint2 rH3B = sH3B[(K + 1) & 3][lane]; /* h3b(I-7), 1-step */               \
    BFrag FBu, FCu, BEu;                                                       \
    FBu.u[0] = FBL2p.x; FBu.u[1] = FBL2p.y;                                    \
    FBu.u[2] = FBL2p.z; FBu.u[3] = FBL2p.w;                                    \
    a30 = MF(A2w0[0], FBu.h, C20);                                             \
    FCu.u[0] = h2bp.x; FCu.u[1] = h2bp.y; FCu.u[2] = fd0; FCu.u[3] = fd1;      \
    a30 = MF(A2w0[1], FCu.h, a30);                                             \
    BEu.u[0] = rH3B.x; BEu.u[1] = rH3B.y; BEu.u[2] = 0u; BEu.u[3] = 0u;        \
    a30 = MF(A2w0[2], BEu.h, a30);                                             \
    __builtin_amdgcn_sched_barrier(0);                                         \
    fd0 = pkr(a30[0], a30[1]); fd1 = pkr(a30[2], a30[3]);                      \
    if (ZH3) { fd0 = fd1 = 0u; }                                               \
    sH3A[(K + 2) & 3][lane] = make_uint2(fd0, fd1);                            \
    __builtin_amdgcn_sched_barrier(0);                                         \
    FBL2p = sH2A[(K + 3) & 3][lane];                                           \
    h2bp  = sH2B[(K + 3) & 3][lane];                                           \
    BAR(2);                                                                    \
  } while (0)

    W3BODY(0, 1); W3BODY(1, 1); W3BODY(2, 1); W3BODY(3, 1);
    W3BODY(0, 1); W3BODY(1, 1); W3BODY(2, 0); W3BODY(3, 0);
#pragma unroll 1
    for (int i = 8; i < TSEQ + 8; i += 4) {
      W3BODY(0, 0); W3BODY(1, 0); W3BODY(2, 0); W3BODY(3, 0);
    }
#undef W3BODY
  }
}

extern "C" void kernel_launch(void* const* d_in, const int* in_sizes, int n_in,
                              void* d_out, int out_size, void* d_ws, size_t ws_size,
                              hipStream_t stream) {
  const float* x    = (const float*)d_in[0];
  const float* wih0 = (const float*)d_in[1];
  const float* whh0 = (const float*)d_in[2];
  const float* bih0 = (const float*)d_in[3];
  const float* bhh0 = (const float*)d_in[4];
  const float* wih1 = (const float*)d_in[5];
  const float* whh1 = (const float*)d_in[6];
  const float* bih1 = (const float*)d_in[7];
  const float* bhh1 = (const float*)d_in[8];
  const float* wih2 = (const float*)d_in[9];
  const float* whh2 = (const float*)d_in[10];
  const float* bih2 = (const float*)d_in[11];
  const float* bhh2 = (const float*)d_in[12];
  const float* wout = (const float*)d_in[13];
  const float* bout = (const float*)d_in[14];
  float* out = (float*)d_out;

  rnn3_pipe<<<dim3(NBAT / 16), dim3(256), 0, stream>>>(
      x, wih0, whh0, bih0, bhh0, wih1, whh1, bih1, bhh1,
      wih2, whh2, bih2, bhh2, wout, bout, out);
}